// Round 1
// baseline (641.118 us; speedup 1.0000x reference)
//
#include <hip/hip_runtime.h>
#include <math.h>

#define N 8192
#define D 64
#define E_K 262144
#define E_HK 262144
#define H_DIM 64

constexpr float INV_KAPPA_K = 0.5f;   // 1/2.0
constexpr float INV_KAPPA_H = 0.5f;   // 1/2.0

// -------- kernel 1: normalize state_K rows, g = tanh(state_H) --------
__global__ __launch_bounds__(256) void prep_kernel(
    const float* __restrict__ state_K, const float* __restrict__ state_H,
    float* __restrict__ Knorm, float* __restrict__ g) {
  int tid  = blockIdx.x * blockDim.x + threadIdx.x;
  int wave = tid >> 6;
  int lane = threadIdx.x & 63;
  if (wave < N) {
    float v = state_K[wave * D + lane];
    float ss = v * v;
    #pragma unroll
    for (int off = 32; off > 0; off >>= 1) ss += __shfl_xor(ss, off);
    float inv = 1.0f / sqrtf(ss);
    Knorm[wave * D + lane] = v * inv;
  }
  if (tid < N) g[tid] = tanhf(state_H[tid]);
}

// -------- kernel 2: f_H = -state_H + W_H @ g (one block per row) --------
__global__ __launch_bounds__(256) void matvec_kernel(
    const float* __restrict__ W_H, const float* __restrict__ g,
    const float* __restrict__ state_H, float* __restrict__ f_H) {
  int row = blockIdx.x;
  const float4* Wrow = reinterpret_cast<const float4*>(W_H + (size_t)row * N);
  const float4* g4   = reinterpret_cast<const float4*>(g);
  float acc = 0.0f;
  #pragma unroll
  for (int c = threadIdx.x; c < N / 4; c += 256) {
    float4 w = Wrow[c];
    float4 gg = g4[c];
    acc += w.x * gg.x + w.y * gg.y + w.z * gg.z + w.w * gg.w;
  }
  #pragma unroll
  for (int off = 32; off > 0; off >>= 1) acc += __shfl_xor(acc, off);
  __shared__ float sbuf[4];
  if ((threadIdx.x & 63) == 0) sbuf[threadIdx.x >> 6] = acc;
  __syncthreads();
  if (threadIdx.x == 0) {
    float r = sbuf[0] + sbuf[1] + sbuf[2] + sbuf[3];
    f_H[row] = -state_H[row] + r;
  }
}

// -------- kernel 3: both edge lists, one wave per edge (lane = d) --------
__global__ __launch_bounds__(256) void edge_kernel(
    const int* __restrict__ ind_HK, const int* __restrict__ ind_K,
    const float* __restrict__ Knorm, const float* __restrict__ g,
    const float* __restrict__ w1, const float* __restrict__ b1,
    const float* __restrict__ w2,
    float* __restrict__ f_H, float* __restrict__ A) {
  int wid  = (blockIdx.x * blockDim.x + threadIdx.x) >> 6;
  int lane = threadIdx.x & 63;
  if (wid < E_HK) {
    int i = ind_HK[wid * 2 + 0];
    int j = ind_HK[wid * 2 + 1];
    float ki = Knorm[i * D + lane];
    float kj = Knorm[j * D + lane];
    float dot = ki * kj;
    #pragma unroll
    for (int off = 32; off > 0; off >>= 1) dot += __shfl_xor(dot, off);
    float gi = g[i], gj = g[j];
    if (lane == 0) {
      atomicAdd(&f_H[i], dot * gj * INV_KAPPA_H);
      atomicAdd(&f_H[j], dot * gi * INV_KAPPA_H);
    }
    float G = gi * gj;
    atomicAdd(&A[i * D + lane], -G * kj * INV_KAPPA_K);
    atomicAdd(&A[j * D + lane], -G * ki * INV_KAPPA_K);
  } else {
    int e = wid - E_HK;
    if (e < E_K) {
      int p = ind_K[e * 2 + 0];
      int q = ind_K[e * 2 + 1];
      float kp = Knorm[p * D + lane];
      float kq = Knorm[q * D + lane];
      float s = kp * kq;
      #pragma unroll
      for (int off = 32; off > 0; off >>= 1) s += __shfl_xor(s, off);
      // dE/ds = sum_k tanh(s*w1[k] + b1[k]) * w2[k], H == 64 == wave size
      float hv = tanhf(s * w1[lane] + b1[lane]) * w2[lane];
      #pragma unroll
      for (int off = 32; off > 0; off >>= 1) hv += __shfl_xor(hv, off);
      atomicAdd(&A[p * D + lane], hv * kq);
      atomicAdd(&A[q * D + lane], hv * kp);
    }
  }
}

// -------- kernel 4: f_K = -A + K * rowdot(K,A) + K @ skew(omega) --------
__global__ __launch_bounds__(256) void finalize_kernel(
    const float* __restrict__ Knorm, const float* __restrict__ A,
    const float* __restrict__ omega, float* __restrict__ f_K) {
  __shared__ float Om[D * D];  // skew-symmetrized omega
  for (int t = threadIdx.x; t < D * D; t += blockDim.x) {
    int a = t / D, b = t % D;
    Om[t] = 0.5f * (omega[a * D + b] - omega[b * D + a]);
  }
  __syncthreads();
  int lane = threadIdx.x & 63;
  int row  = blockIdx.x * (blockDim.x >> 6) + (threadIdx.x >> 6);
  if (row >= N) return;
  float k = Knorm[row * D + lane];
  float a = A[row * D + lane];
  float rd = k * a;
  #pragma unroll
  for (int off = 32; off > 0; off >>= 1) rd += __shfl_xor(rd, off);
  float ko = 0.0f;
  #pragma unroll
  for (int dd = 0; dd < D; ++dd) {
    float kd = __shfl(k, dd);
    ko += kd * Om[dd * D + lane];
  }
  f_K[row * D + lane] = -a + k * rd + ko;
}

extern "C" void kernel_launch(void* const* d_in, const int* in_sizes, int n_in,
                              void* d_out, int out_size, void* d_ws, size_t ws_size,
                              hipStream_t stream) {
  const float* state_H = (const float*)d_in[0];
  const float* state_K = (const float*)d_in[1];
  const float* W_H     = (const float*)d_in[2];
  const float* omega   = (const float*)d_in[3];
  const float* w1      = (const float*)d_in[4];
  const float* b1      = (const float*)d_in[5];
  const float* w2      = (const float*)d_in[6];
  const int*   ind_K   = (const int*)d_in[7];
  const int*   ind_HK  = (const int*)d_in[8];

  float* f_H = (float*)d_out;       // N
  float* f_K = (float*)d_out + N;   // N*D

  float* Knorm = (float*)d_ws;      // N*D floats
  float* g     = Knorm + N * D;     // N floats
  float* A     = g + N;             // N*D floats (f_K scatter accumulator)

  hipMemsetAsync(A, 0, (size_t)N * D * sizeof(float), stream);

  prep_kernel<<<(N * 64 + 255) / 256, 256, 0, stream>>>(state_K, state_H, Knorm, g);

  matvec_kernel<<<N, 256, 0, stream>>>(W_H, g, state_H, f_H);

  int totalWaves = E_HK + E_K;
  edge_kernel<<<(totalWaves * 64) / 256, 256, 0, stream>>>(
      ind_HK, ind_K, Knorm, g, w1, b1, w2, f_H, A);

  finalize_kernel<<<(N + 3) / 4, 256, 0, stream>>>(Knorm, A, omega, f_K);
}